// Round 1
// baseline (327.171 us; speedup 1.0000x reference)
//
#include <hip/hip_runtime.h>
#include <cstdint>

// ---------------------------------------------------------------------------
// K1: 1x1 conv 256->8 on 64x64 maps. x[4,256,64,64] * w[8,256] + b[8]
// block = 256 threads = (4 c-groups x 64 pixels), one (b,row) per block.
// Split-K partials reduced through LDS. grid = 4*64 = 256 blocks.
// ---------------------------------------------------------------------------
__global__ __launch_bounds__(256) void k_conv(const float* __restrict__ x,
                                              const float* __restrict__ w,
                                              const float* __restrict__ bias,
                                              float* __restrict__ y) {
  __shared__ float wl[2048];          // conv_w [8][256]
  __shared__ float red[4][64][9];     // pad 9: conflict-free
  const int tid = threadIdx.x;
#pragma unroll
  for (int i = 0; i < 8; i++) { int idx = tid + i * 256; wl[idx] = w[idx]; }
  const int bi = blockIdx.x >> 6, row = blockIdx.x & 63;
  const int hwi = tid & 63, cg = tid >> 6;
  const float* xp = x + (((size_t)(bi * 256 + cg * 64)) * 64 + row) * 64 + hwi;
  float acc[8] = {0.f, 0.f, 0.f, 0.f, 0.f, 0.f, 0.f, 0.f};
  __syncthreads();
#pragma unroll 4
  for (int c = 0; c < 64; c++) {
    float v = xp[(size_t)c * 4096];
#pragma unroll
    for (int o = 0; o < 8; o++) acc[o] += v * wl[o * 256 + cg * 64 + c];
  }
#pragma unroll
  for (int o = 0; o < 8; o++) red[cg][hwi][o] = acc[o];
  __syncthreads();
#pragma unroll
  for (int i = 0; i < 2; i++) {
    int p = tid + i * 256; int o = p >> 6, hw = p & 63;
    float sv = red[0][hw][o] + red[1][hw][o] + red[2][hw][o] + red[3][hw][o] + bias[o];
    y[(((size_t)(bi * 8 + o)) * 64 + row) * 64 + hw] = sv;
  }
}

// ---------------------------------------------------------------------------
// K2: bilinear-upsample(64->512, align_corners) argmax over 8ch, 4x4 mean
// pool of one-hot -> fm[4,8,128,128]. One thread per pooled cell (16 pixels).
// grid = 4*128*128/256 = 256 blocks.
// ---------------------------------------------------------------------------
__global__ __launch_bounds__(256) void k_pool(const float* __restrict__ ys,
                                              float* __restrict__ fm) {
  const int g = blockIdx.x * 256 + threadIdx.x;
  const int bi = g >> 14, rem = g & 16383;
  const int sm = rem >> 7, tm = rem & 127;
  int cnt[8] = {0, 0, 0, 0, 0, 0, 0, 0};
  const float* yb = ys + (size_t)bi * 8 * 4096;
#pragma unroll
  for (int py = 0; py < 4; py++) {
    const int s = sm * 4 + py;
    float ph = s * (63.0f / 511.0f); int lh = (int)ph; float wh = ph - (float)lh;
    const int dh = (lh < 63) ? 64 : 0;
#pragma unroll
    for (int px = 0; px < 4; px++) {
      const int t = tm * 4 + px;
      float pw = t * (63.0f / 511.0f); int lt = (int)pw; float wt = pw - (float)lt;
      const int dt = (lt < 63) ? 1 : 0;
      const float w00 = (1.f - wh) * (1.f - wt), w01 = (1.f - wh) * wt;
      const float w10 = wh * (1.f - wt), w11 = wh * wt;
      const int base = lh * 64 + lt;
      float best = 0.f; int am = 0;
#pragma unroll
      for (int c = 0; c < 8; c++) {
        const float* yc = yb + c * 4096 + base;
        float v = w00 * yc[0] + w01 * yc[dt] + w10 * yc[dh] + w11 * yc[dh + dt];
        if (c == 0) { best = v; } else if (v > best) { best = v; am = c; }
      }
#pragma unroll
      for (int c = 0; c < 8; c++) cnt[c] += (am == c);  // static idx, no scratch
    }
  }
  const size_t ob = ((size_t)bi * 8) << 14;
#pragma unroll
  for (int c = 0; c < 8; c++)
    fm[ob + ((size_t)c << 14) + (sm << 7) + tm] = (float)cnt[c] * (1.0f / 16.0f);
}

// ---------------------------------------------------------------------------
// K4 (fused): per (b,c): corr_raw[4096,64] = A[4096,256] @ U^T  where
// U[p][l] = unfold(fm). ALSO: passthrough-copy A to out2 and count nonzeros
// per row -> nzinv (free riders on the A staging loads).
// Block: 256 q-rows, 512 threads (8 p-groups x 64 q-lane-groups).
// LDS: At[32][260] k-major (pad: b128 reads conflict-free), Uts[32][64]
// rebuilt per 32-k chunk from fm (L2-hot), broadcast b128 reads.
// T14: issue next chunk's loads before compute, write after barrier.
// grid = (4096/256=16, 32 bc).
// ---------------------------------------------------------------------------
__global__ __launch_bounds__(512, 4) void k_corr(const float* __restrict__ A,
                                                 const float* __restrict__ fm,
                                                 float* __restrict__ Aout,
                                                 float* __restrict__ corr,
                                                 float* __restrict__ nzinv) {
  __shared__ __align__(16) float At[32][260];
  __shared__ __align__(16) float Uts[32][64];
  __shared__ int nzc[256];
  const int tid = threadIdx.x;
  const int bc = blockIdx.y;
  const int qb = blockIdx.x << 8;
  const float* Ab = A + ((size_t)bc * 4096 + qb) * 256;
  float* Ob = Aout + ((size_t)bc * 4096 + qb) * 256;
  const float* fmb = fm + ((size_t)bc << 14);
  if (tid < 256) nzc[tid] = 0;
  const int lane = tid & 63, pg = tid >> 6, p0 = pg << 3;

  int fq[4], fk[4], ekk[4], ep[4];
#pragma unroll
  for (int i = 0; i < 4; i++) {
    const int f = tid + i * 512;
    fq[i] = f >> 3; fk[i] = (f & 7) * 4;   // A loader: row, k-offset
    ekk[i] = f >> 6; ep[i] = f & 63;       // U loader: kk, p
  }

  float4 ar[4]; float ur[4];
  // ---- prologue: chunk 0 loads ----
#pragma unroll
  for (int i = 0; i < 4; i++) ar[i] = *(const float4*)(Ab + (size_t)fq[i] * 256 + fk[i]);
#pragma unroll
  for (int i = 0; i < 4; i++) {
    const int l = ekk[i], p = ep[i];
    ur[i] = fmb[((l >> 4) * 8 + (p >> 3)) * 128 + (l & 15) * 8 + (p & 7)];
  }
  __syncthreads();  // nzc zeroed before atomics
#pragma unroll
  for (int i = 0; i < 4; i++) {
    At[fk[i] + 0][fq[i]] = ar[i].x; At[fk[i] + 1][fq[i]] = ar[i].y;
    At[fk[i] + 2][fq[i]] = ar[i].z; At[fk[i] + 3][fq[i]] = ar[i].w;
    *(float4*)(Ob + (size_t)fq[i] * 256 + fk[i]) = ar[i];
    int c4 = (ar[i].x != 0.f) + (ar[i].y != 0.f) + (ar[i].z != 0.f) + (ar[i].w != 0.f);
    c4 += __shfl_xor(c4, 1); c4 += __shfl_xor(c4, 2); c4 += __shfl_xor(c4, 4);
    if ((tid & 7) == 0) atomicAdd(&nzc[fq[i]], c4);
    Uts[ekk[i]][ep[i]] = ur[i];
  }
  __syncthreads();

  float acc[4][8];
#pragma unroll
  for (int j = 0; j < 4; j++)
#pragma unroll
    for (int i = 0; i < 8; i++) acc[j][i] = 0.f;

  for (int c = 0; c < 8; c++) {
    if (c < 7) {  // issue-early (T14): next chunk's global loads in flight
      const int kc = (c + 1) * 32;
#pragma unroll
      for (int i = 0; i < 4; i++) ar[i] = *(const float4*)(Ab + (size_t)fq[i] * 256 + kc + fk[i]);
#pragma unroll
      for (int i = 0; i < 4; i++) {
        const int l = kc + ekk[i], p = ep[i];
        ur[i] = fmb[((l >> 4) * 8 + (p >> 3)) * 128 + (l & 15) * 8 + (p & 7)];
      }
    }
    // ---- compute current chunk ----
#pragma unroll 8
    for (int kk = 0; kk < 32; kk++) {
      float4 a = *(const float4*)&At[kk][lane << 2];          // b128, conflict-free
      float4 u0 = *(const float4*)&Uts[kk][p0];               // broadcast b128
      float4 u1 = *(const float4*)&Uts[kk][p0 + 4];
      const float av[4] = {a.x, a.y, a.z, a.w};
      const float uv[8] = {u0.x, u0.y, u0.z, u0.w, u1.x, u1.y, u1.z, u1.w};
#pragma unroll
      for (int j = 0; j < 4; j++)
#pragma unroll
        for (int i = 0; i < 8; i++) acc[j][i] += av[j] * uv[i];
    }
    __syncthreads();  // all waves done reading At/Uts
    if (c < 7) {      // write-late: stage next chunk, passthrough, nz count
      const int kc = (c + 1) * 32;
#pragma unroll
      for (int i = 0; i < 4; i++) {
        At[fk[i] + 0][fq[i]] = ar[i].x; At[fk[i] + 1][fq[i]] = ar[i].y;
        At[fk[i] + 2][fq[i]] = ar[i].z; At[fk[i] + 3][fq[i]] = ar[i].w;
        *(float4*)(Ob + (size_t)fq[i] * 256 + kc + fk[i]) = ar[i];
        int c4 = (ar[i].x != 0.f) + (ar[i].y != 0.f) + (ar[i].z != 0.f) + (ar[i].w != 0.f);
        c4 += __shfl_xor(c4, 1); c4 += __shfl_xor(c4, 2); c4 += __shfl_xor(c4, 4);
        if ((tid & 7) == 0) atomicAdd(&nzc[fq[i]], c4);
        Uts[ekk[i]][ep[i]] = ur[i];
      }
    }
    __syncthreads();
  }

  if (tid < 256) nzinv[(size_t)bc * 4096 + qb + tid] = 1.0f / ((float)nzc[tid] + 1e-5f);

  float* cb = corr + (((size_t)bc * 4096 + qb + (lane << 2)) << 6) + p0;
#pragma unroll
  for (int j = 0; j < 4; j++) {
    float4 o0 = make_float4(acc[j][0], acc[j][1], acc[j][2], acc[j][3]);
    float4 o1 = make_float4(acc[j][4], acc[j][5], acc[j][6], acc[j][7]);
    *(float4*)(cb + ((size_t)j << 6)) = o0;
    *(float4*)(cb + ((size_t)j << 6) + 4) = o1;
  }
}

// ---------------------------------------------------------------------------
// K5: out = log_softmax_c( (corr[q,p]/nz + 1) * bilinear_up(y_small) )
// One thread per output pixel; y_small taps are L1/L2-resident.
// grid = 4*512*512/256 = 4096 blocks.
// ---------------------------------------------------------------------------
__global__ __launch_bounds__(256) void k_out(const float* __restrict__ corr,
                                             const float* __restrict__ nzinv,
                                             const float* __restrict__ ys,
                                             float* __restrict__ out) {
  const int g = blockIdx.x * 256 + threadIdx.x;
  const int b = g >> 18; const int s = (g >> 9) & 511; const int t = g & 511;
  const int q = ((s >> 3) << 6) + (t >> 3);
  const int p = ((s & 7) << 3) + (t & 7);
  float ph = s * (63.0f / 511.0f); int lh = (int)ph; float wh = ph - (float)lh;
  const int dh = (lh < 63) ? 64 : 0;
  float pw = t * (63.0f / 511.0f); int lt = (int)pw; float wt = pw - (float)lt;
  const int dt = (lt < 63) ? 1 : 0;
  const float w00 = (1.f - wh) * (1.f - wt), w01 = (1.f - wh) * wt;
  const float w10 = wh * (1.f - wt), w11 = wh * wt;
  const int base = lh * 64 + lt;
  float z[8];
#pragma unroll
  for (int c = 0; c < 8; c++) {
    const size_t bcp = (size_t)(b * 8 + c);
    const float cr = corr[(((bcp << 12) + q) << 6) + p];
    const float rz = nzinv[(bcp << 12) + q];
    const float* yc = ys + (bcp << 12) + base;
    const float yv = w00 * yc[0] + w01 * yc[dt] + w10 * yc[dh] + w11 * yc[dh + dt];
    z[c] = (cr * rz + 1.0f) * yv;
  }
  float m = z[0];
#pragma unroll
  for (int c = 1; c < 8; c++) m = fmaxf(m, z[c]);
  float sum = 0.f;
#pragma unroll
  for (int c = 0; c < 8; c++) sum += __expf(z[c] - m);
  const float ls = __logf(sum);
  const size_t ob = ((size_t)b << 21) + (s << 9) + t;
#pragma unroll
  for (int c = 0; c < 8; c++) out[ob + ((size_t)c << 18)] = z[c] - m - ls;
}

// ---------------------------------------------------------------------------
extern "C" void kernel_launch(void* const* d_in, const int* in_sizes, int n_in,
                              void* d_out, int out_size, void* d_ws, size_t ws_size,
                              hipStream_t stream) {
  const float* x   = (const float*)d_in[0];   // [4,256,64,64]
  const float* att = (const float*)d_in[1];   // [4,8,4096,256]
  const float* cw  = (const float*)d_in[2];   // [8,256]
  const float* cb  = (const float*)d_in[3];   // [8]
  float* out1 = (float*)d_out;                          // [4,8,512,512]
  float* out2 = out1 + (size_t)4 * 8 * 512 * 512;       // attentions passthrough
  float* ws = (float*)d_ws;
  float* y_small = ws;                 // 131072  [4,8,64,64]
  float* fm      = ws + 131072;        // 524288  [4,8,128,128]
  float* nzinv   = ws + 655360;        // 131072  [4,8,4096]
  float* corr    = ws + 786432;        // 8388608 [4,8,4096,64]  (total 36.7 MB)

  k_conv<<<256, 256, 0, stream>>>(x, cw, cb, y_small);
  k_pool<<<256, 256, 0, stream>>>(y_small, fm);
  dim3 g4(16, 32);
  k_corr<<<g4, 512, 0, stream>>>(att, fm, out2, corr, nzinv);
  k_out<<<4096, 256, 0, stream>>>(corr, nzinv, y_small, out1);
}